// Round 5
// baseline (122.041 us; speedup 1.0000x reference)
//
#include <hip/hip_runtime.h>
#include <hip/hip_fp16.h>

constexpr int kNodes = 50000;
constexpr int kEdges = 500000;
constexpr int kInF   = 128;
constexpr int kOutF  = 16;

typedef float    f32x4  __attribute__((ext_vector_type(4)));
typedef __fp16   h16x2  __attribute__((ext_vector_type(2)));  // cvt_pkrtz's type
typedef _Float16 f16x4  __attribute__((ext_vector_type(4)));
typedef _Float16 f16x8  __attribute__((ext_vector_type(8)));

static __device__ inline unsigned int pack_f16(float a, float b) {
  const h16x2 h = __builtin_amdgcn_cvt_pkrtz(a, b);
  return __builtin_bit_cast(unsigned int, h);
}

// ---------------------------------------------------------------------------
// Kernel 1: support_h[n][f] = (f16) sum_k x[n][k]*W[k][f];  out_h[n][f] = 0.
// 4 threads per node, thread owns one quarter (4 outputs).
// ---------------------------------------------------------------------------
__global__ __launch_bounds__(256) void support_init_kernel(
    const float* __restrict__ x, const float* __restrict__ weight,
    _Float16* __restrict__ support_h, _Float16* __restrict__ out_h) {
  __shared__ f32x4 w4[kInF][kOutF / 4];  // w4[k][f4]
  for (int i = threadIdx.x; i < kInF * (kOutF / 4); i += 256) {
    w4[i / (kOutF / 4)][i % (kOutF / 4)] =
        reinterpret_cast<const f32x4*>(weight)[i];
  }
  __syncthreads();

  const int gid  = blockIdx.x * 256 + threadIdx.x;
  const int node = gid >> 2;
  const int f4   = gid & 3;
  if (node >= kNodes) return;

  f32x4 acc = {0.f, 0.f, 0.f, 0.f};
  const f32x4* xr = reinterpret_cast<const f32x4*>(x + (size_t)node * kInF);
#pragma unroll
  for (int k4 = 0; k4 < kInF / 4; ++k4) {
    const f32x4 v = xr[k4];
#pragma unroll
    for (int kk = 0; kk < 4; ++kk) {
      acc += v[kk] * w4[k4 * 4 + kk][f4];
    }
  }

  uint2 pack;
  pack.x = pack_f16(acc.x, acc.y);
  pack.y = pack_f16(acc.z, acc.w);
  reinterpret_cast<uint2*>(support_h + (size_t)node * kOutF)[f4] = pack;

  const uint2 z = {0u, 0u};
  reinterpret_cast<uint2*>(out_h + (size_t)node * kOutF)[f4] = z;
}

// ---------------------------------------------------------------------------
// Kernel 2: 8 lanes per edge; lane owns row pair (2r, 2r+1) = 128 B of
// edge_data (contiguous per lane). Gather is 32 B f16 (L1-broadcast across
// the 8 lanes). One packed f16 atomic per lane -> 4M atomics total.
// ---------------------------------------------------------------------------
__global__ __launch_bounds__(256) void edge_kernel(
    const float* __restrict__ edge_data,
    const _Float16* __restrict__ support_h, const int* __restrict__ esrc,
    const int* __restrict__ etgt, _Float16* __restrict__ out_h) {
  const int gid = blockIdx.x * 256 + threadIdx.x;  // grid is exact: kEdges*8
  const int e  = gid >> 3;
  const int rp = gid & 7;  // row pair index

  const int src = esrc[e];
  const int tgt = etgt[e];

  const f16x8* sp =
      reinterpret_cast<const f16x8*>(support_h + (size_t)src * kOutF);
  const f16x8 sa = sp[0], sb = sp[1];
  float s[16];
#pragma unroll
  for (int j = 0; j < 8; ++j) {
    s[j]     = (float)sa[j];
    s[8 + j] = (float)sb[j];
  }

  const f32x4* ed = reinterpret_cast<const f32x4*>(
      edge_data + (size_t)e * (kOutF * kOutF) + (size_t)rp * 2 * kOutF);
  float acc0 = 0.f, acc1 = 0.f;
#pragma unroll
  for (int q = 0; q < 4; ++q) {
    const f32x4 a = ed[q];      // row 2*rp
    const f32x4 b = ed[4 + q];  // row 2*rp+1
    acc0 += a.x * s[4 * q] + a.y * s[4 * q + 1] + a.z * s[4 * q + 2] +
            a.w * s[4 * q + 3];
    acc1 += b.x * s[4 * q] + b.y * s[4 * q + 1] + b.z * s[4 * q + 2] +
            b.w * s[4 * q + 3];
  }

  const unsigned int bits = pack_f16(acc0, acc1);
  _Float16* dst = out_h + (size_t)tgt * kOutF + rp * 2;
  asm volatile("global_atomic_pk_add_f16 %0, %1, off" ::"v"(dst), "v"(bits)
               : "memory");
}

// ---------------------------------------------------------------------------
// Kernel 3: out[n][f] = (float)out_h[n][f] + bias[f]
// ---------------------------------------------------------------------------
__global__ __launch_bounds__(256) void finalize_kernel(
    const _Float16* __restrict__ out_h, const float* __restrict__ bias,
    float* __restrict__ out) {
  const int tid = blockIdx.x * 256 + threadIdx.x;
  if (tid >= kNodes * 4) return;
  const int node = tid >> 2;
  const int q    = tid & 3;

  const f16x4 h = reinterpret_cast<const f16x4*>(out_h + (size_t)node * kOutF)[q];
  const f32x4 b = reinterpret_cast<const f32x4*>(bias)[q];
  f32x4 o;
  o.x = (float)h[0] + b.x;
  o.y = (float)h[1] + b.y;
  o.z = (float)h[2] + b.z;
  o.w = (float)h[3] + b.w;
  reinterpret_cast<f32x4*>(out + (size_t)node * kOutF)[q] = o;
}

// ---------------------------------------------------------------------------
extern "C" void kernel_launch(void* const* d_in, const int* in_sizes, int n_in,
                              void* d_out, int out_size, void* d_ws,
                              size_t ws_size, hipStream_t stream) {
  const float* x         = (const float*)d_in[0];
  const float* weight    = (const float*)d_in[1];
  const float* bias      = (const float*)d_in[2];
  const float* edge_data = (const float*)d_in[3];
  const int*   esrc      = (const int*)d_in[4];
  const int*   etgt      = (const int*)d_in[5];
  float* out = (float*)d_out;

  _Float16* support_h = (_Float16*)d_ws;                          // 1.6 MB
  _Float16* out_h     = (_Float16*)d_ws + (size_t)kNodes * kOutF; // 1.6 MB

  support_init_kernel<<<(kNodes * 4 + 255) / 256, 256, 0, stream>>>(
      x, weight, support_h, out_h);
  edge_kernel<<<kEdges * 8 / 256, 256, 0, stream>>>(edge_data, support_h, esrc,
                                                    etgt, out_h);
  finalize_kernel<<<(kNodes * 4 + 255) / 256, 256, 0, stream>>>(out_h, bias,
                                                                out);
}

// Round 6
// 107.908 us; speedup vs baseline: 1.1310x; 1.1310x over previous
//
#include <hip/hip_runtime.h>

constexpr int kNodes = 50000;
constexpr int kEdges = 500000;
constexpr int kInF   = 128;
constexpr int kOutF  = 16;

typedef float f32x4 __attribute__((ext_vector_type(4)));

// ---------------------------------------------------------------------------
// Kernel 1 (fused): support[n][f] = sum_k x[n][k]*W[k][f]  AND  out[n][f]=bias[f]
// 4 threads per node; thread owns one float4 (f4) of the 16 outputs.
// (unchanged from the 112 µs round-3 kernel)
// ---------------------------------------------------------------------------
__global__ __launch_bounds__(256) void support_init_kernel(
    const float* __restrict__ x, const float* __restrict__ weight,
    const float* __restrict__ bias, float* __restrict__ support,
    float* __restrict__ out) {
  __shared__ f32x4 w4[kInF][kOutF / 4];  // w4[k][f4]
  for (int i = threadIdx.x; i < kInF * (kOutF / 4); i += 256) {
    w4[i / (kOutF / 4)][i % (kOutF / 4)] =
        reinterpret_cast<const f32x4*>(weight)[i];
  }
  __shared__ f32x4 b4[kOutF / 4];
  if (threadIdx.x < kOutF / 4)
    b4[threadIdx.x] = reinterpret_cast<const f32x4*>(bias)[threadIdx.x];
  __syncthreads();

  const int gid  = blockIdx.x * 256 + threadIdx.x;
  const int node = gid >> 2;
  const int f4   = gid & 3;
  if (node >= kNodes) return;

  f32x4 acc = {0.f, 0.f, 0.f, 0.f};
  const f32x4* xr = reinterpret_cast<const f32x4*>(x + (size_t)node * kInF);
#pragma unroll
  for (int k4 = 0; k4 < kInF / 4; ++k4) {
    const f32x4 v = xr[k4];
#pragma unroll
    for (int kk = 0; kk < 4; ++kk) {
      acc += v[kk] * w4[k4 * 4 + kk][f4];
    }
  }

  reinterpret_cast<f32x4*>(support + (size_t)node * kOutF)[f4] = acc;
  reinterpret_cast<f32x4*>(out + (size_t)node * kOutF)[f4] = b4[f4];
}

// ---------------------------------------------------------------------------
// Kernel 2: whole-wave-per-edge. Lane l owns (row r=l&15, quarter q=l>>4):
//   stream load : 1 instr/edge, 64 lanes x 16 B = the edge's 1 KB CONTIGUOUS
//   gather      : 1 instr/edge, all lanes within one 64 B support row
//   dot finish  : __shfl_xor 16 + 32 (sums the 4 quarters of each row)
//   atomic      : 1 instr/edge, lanes 0..15 -> 16 consecutive dwords (1 line)
// 8 edges per wave, loads batched up-front for MLP (full unroll -> static reg
// indexing), atomics issued after all loads are in flight.
// ---------------------------------------------------------------------------
constexpr int kEPW = 8;  // edges per wave; kEdges % (4 waves * kEPW) == 0

__global__ __launch_bounds__(256) void edge_kernel(
    const float* __restrict__ edge_data, const float* __restrict__ support,
    const int* __restrict__ esrc, const int* __restrict__ etgt,
    float* __restrict__ out) {
  const int wave = (blockIdx.x * 256 + threadIdx.x) >> 6;
  const int l    = threadIdx.x & 63;
  const int r    = l & 15;   // output row this lane reduces
  const int q    = l >> 4;   // which 4-column quarter this lane loads
  const int e0   = wave * kEPW;

  const f32x4* ed4 = reinterpret_cast<const f32x4*>(edge_data);
  const f32x4* sp4 = reinterpret_cast<const f32x4*>(support);

  f32x4 row[kEPW];
  f32x4 sv[kEPW];
  int   tgt[kEPW];

#pragma unroll
  for (int k = 0; k < kEPW; ++k) {
    const int e  = e0 + k;
    const int s  = esrc[e];
    tgt[k]       = etgt[e];
    sv[k]        = sp4[(size_t)s * 4 + q];
    row[k]       = ed4[(size_t)e * 64 + (r * 4 + q)];
  }

#pragma unroll
  for (int k = 0; k < kEPW; ++k) {
    float dot = row[k].x * sv[k].x + row[k].y * sv[k].y + row[k].z * sv[k].z +
                row[k].w * sv[k].w;
    dot += __shfl_xor(dot, 16);
    dot += __shfl_xor(dot, 32);
    if (q == 0) atomicAdd(&out[(size_t)tgt[k] * kOutF + r], dot);
  }
}

// ---------------------------------------------------------------------------
extern "C" void kernel_launch(void* const* d_in, const int* in_sizes, int n_in,
                              void* d_out, int out_size, void* d_ws,
                              size_t ws_size, hipStream_t stream) {
  const float* x         = (const float*)d_in[0];
  const float* weight    = (const float*)d_in[1];
  const float* bias      = (const float*)d_in[2];
  const float* edge_data = (const float*)d_in[3];
  const int*   esrc      = (const int*)d_in[4];
  const int*   etgt      = (const int*)d_in[5];
  float* out = (float*)d_out;

  float* support = (float*)d_ws;  // kNodes * kOutF * 4 B = 3.2 MB

  support_init_kernel<<<(kNodes * 4 + 255) / 256, 256, 0, stream>>>(
      x, weight, bias, support, out);

  // 4 waves/block * kEPW edges/wave = 32 edges per block
  edge_kernel<<<kEdges / (4 * kEPW), 256, 0, stream>>>(edge_data, support,
                                                       esrc, etgt, out);
}